// Round 10
// baseline (1137.649 us; speedup 1.0000x reference)
//
#include <hip/hip_runtime.h>

typedef unsigned short u16;
typedef __attribute__((ext_vector_type(8))) short short8;
typedef __attribute__((ext_vector_type(4))) short short4_t;
typedef __attribute__((ext_vector_type(4))) float f32x4;

#define NLAYER 6
#define NH 16
#define DMODEL 1024
#define DHEAD 64
#define NVOCAB 32000
#define NB 2
#define NS 1024
#define NDFF 4096
#define MTOK (NB*NS)   // 2048

__device__ __forceinline__ u16 f2b(float f) {
    union { float f; unsigned u; } x; x.f = f;
    unsigned r = x.u + 0x7fffu + ((x.u >> 16) & 1u);
    return (u16)(r >> 16);
}

#define GLL16(gp, lp) __builtin_amdgcn_global_load_lds( \
    (const __attribute__((address_space(1))) void*)(gp), \
    (__attribute__((address_space(3))) void*)(lp), 16, 0, 0)

// ---------------------------------------------------------------------------
__global__ __launch_bounds__(256) void trans64(
    const float* __restrict__ src, u16* __restrict__ dst,
    int R, int C, long sStride, long dStride)
{
    __shared__ float sh[64][65];
    const int c0 = blockIdx.x * 64, r0 = blockIdx.y * 64;
    const float* s = src + (long)blockIdx.z * sStride;
    u16* d = dst + (long)blockIdx.z * dStride;
    const int tid = threadIdx.x;
    const int lr = tid >> 4, lc = (tid & 15) * 4;
    #pragma unroll
    for (int q = 0; q < 4; ++q) {
        const float4 v = *(const float4*)(s + (long)(r0 + q * 16 + lr) * C + c0 + lc);
        sh[q * 16 + lr][lc + 0] = v.x;
        sh[q * 16 + lr][lc + 1] = v.y;
        sh[q * 16 + lr][lc + 2] = v.z;
        sh[q * 16 + lr][lc + 3] = v.w;
    }
    __syncthreads();
    #pragma unroll
    for (int k = 0; k < 2; ++k) {
        const int t = tid + 256 * k;
        const int col = t >> 3, rch = (t & 7) * 8;
        u16 tmp[8];
        #pragma unroll
        for (int j = 0; j < 8; ++j) tmp[j] = f2b(sh[rch + j][col]);
        *(short8*)(d + (long)(c0 + col) * R + r0 + rch) = *(const short8*)tmp;
    }
}

// Wq/Wk/Wv merged: z = sel*96 + (l*16+h)
__global__ void transpose_qkv(const float* __restrict__ Wq, const float* __restrict__ Wk,
                              const float* __restrict__ Wv, u16* __restrict__ dst)
{
    __shared__ float t[32][33];
    const int sel = blockIdx.z / 96, bi = blockIdx.z % 96;
    const int l = bi >> 4, h = bi & 15;
    const float* srcs[3] = { Wq, Wk, Wv };
    const float* s = srcs[sel] + (long)bi * (DMODEL * DHEAD);
    u16* d = dst + (long)l * 3072 * DMODEL + (long)(sel * 1024 + h * 64) * DMODEL;
    const int c0 = blockIdx.x * 32, r0 = blockIdx.y * 32;
    const int tx = threadIdx.x, ty = threadIdx.y;
    #pragma unroll
    for (int j = 0; j < 32; j += 8)
        t[ty + j][tx] = s[(long)(r0 + ty + j) * DHEAD + c0 + tx];
    __syncthreads();
    #pragma unroll
    for (int j = 0; j < 32; j += 8)
        d[(long)(c0 + ty + j) * DMODEL + r0 + tx] = f2b(t[tx][ty + j]);
}

// ---------------------------------------------------------------------------
__global__ void embed_pe(const int* __restrict__ toks, const float* __restrict__ emb,
                         float* __restrict__ x, u16* __restrict__ xb)
{
    const int row = blockIdx.x;
    const int s = row & (NS - 1);
    const long erow = (long)toks[row] * DMODEL;
    const long base = (long)row * DMODEL;
    #pragma unroll
    for (int j = 0; j < 4; ++j) {
        int d = threadIdx.x + j * 256;
        float ang = (float)s * exp2f(-(float)d * (9.965784284662087f / 1024.f));
        float pe = (d & 1) ? cosf(ang) : sinf(ang);
        float v = emb[erow + d] + pe;
        x[base + d] = v;
        xb[base + d] = f2b(v);
    }
}

// ---------------------------------------------------------------------------
template<int ND>
__global__ __launch_bounds__(256) void ln_residual(
    const float* __restrict__ xin, const float* __restrict__ delta, size_t pstride,
    const float* __restrict__ g, const float* __restrict__ bb,
    float* __restrict__ xout, u16* __restrict__ xbout)
{
    __shared__ float red[8];
    const long base = (long)blockIdx.x * DMODEL;
    const int d = threadIdx.x * 4;
    f32x4 v = *(const f32x4*)(xin + base + d);
    #pragma unroll
    for (int y = 0; y < ND; ++y)
        v += *(const f32x4*)(delta + base + (size_t)y * pstride + d);
    float sum = v[0] + v[1] + v[2] + v[3];
    float sq  = v[0]*v[0] + v[1]*v[1] + v[2]*v[2] + v[3]*v[3];
    #pragma unroll
    for (int off = 1; off < 64; off <<= 1) {
        sum += __shfl_xor(sum, off, 64);
        sq  += __shfl_xor(sq,  off, 64);
    }
    const int wv = threadIdx.x >> 6, lane = threadIdx.x & 63;
    if (lane == 0) { red[wv] = sum; red[4 + wv] = sq; }
    __syncthreads();
    float ts = red[0] + red[1] + red[2] + red[3];
    float tq = red[4] + red[5] + red[6] + red[7];
    float mu = ts * (1.f / DMODEL);
    float var = tq * (1.f / DMODEL) - mu * mu;
    float rstd = rsqrtf(var + 1e-5f);
    const f32x4 gg = *(const f32x4*)(g + d);
    const f32x4 bv = *(const f32x4*)(bb + d);
    f32x4 yv = (v - mu) * rstd * gg + bv;
    *(f32x4*)(xout + base + d) = yv;
    u16 fourv[4];
    #pragma unroll
    for (int i = 0; i < 4; ++i) fourv[i] = f2b(yv[i]);
    *(short4_t*)(xbout + base + d) = *(const short4_t*)fourv;
}

// ---------------------------------------------------------------------------
// r5-proven pipelined GEMM body (16x16x32, BK=32, 4 LDS slots, vmcnt(8),
// XOR swizzle, XCD swizzle).
template<int BM, int EPI>
__device__ __forceinline__ void gemm_body(
    const u16* __restrict__ A, const u16* __restrict__ Bt,
    void* __restrict__ Cout, const float* __restrict__ bias,
    int M, int N, int K, int lda, int ldb, size_t zstride,
    int id, int nwg, int zidx, u16* Asp, u16* Bsp)
{
    constexpr int WAVES = BM / 32;
    constexpr int WC = WAVES / 2;
    constexpr int MR = BM / 32;
    constexpr int TILE = BM * 32;

    const int nmb = M / BM;
    const int q = nwg >> 3, r = nwg & 7, xcd = id & 7, loc = id >> 3;
    const int swz = (xcd < r ? xcd * (q + 1) : r * (q + 1) + (xcd - r) * q) + loc;
    const int m0 = (swz % nmb) * BM, n0 = (swz / nmb) * BM;
    const int koff = zidx * K;

    const int tid = threadIdx.x, wv = tid >> 6, lane = tid & 63;
    const int wr = wv / WC, wc = wv % WC;
    const int lrow = lane & 15, ks = lane >> 4;

    const u16* gsrc[4];
    int ldso[2];
    {
        const int l4 = lane >> 2, s = lane & 3;
        #pragma unroll
        for (int j = 0; j < 2; ++j) {
            const int row = j * (WAVES * 16) + wv * 16 + l4;
            const int x = (row >> 1) & 3;
            gsrc[j]     = A  + (size_t)(m0 + row) * lda + koff + (size_t)((s ^ x) * 8);
            gsrc[2 + j] = Bt + (size_t)(n0 + row) * ldb + koff + (size_t)((s ^ x) * 8);
            ldso[j] = (j * (WAVES * 16) + wv * 16) * 32;
        }
    }
    int aoff[MR], boff[4];
    #pragma unroll
    for (int m = 0; m < MR; ++m) {
        const int row = wr * (BM / 2) + m * 16 + lrow;
        aoff[m] = row * 32 + ((ks ^ ((row >> 1) & 3)) * 8);
    }
    #pragma unroll
    for (int n = 0; n < 4; ++n) {
        const int row = wc * 64 + n * 16 + lrow;
        boff[n] = row * 32 + ((ks ^ ((row >> 1) & 3)) * 8);
    }

    const int NT = K / 32;
    auto ISSUE = [&](int t) {
        const int b = t & 3;
        const size_t ko = (size_t)t * 32;
        #pragma unroll
        for (int j = 0; j < 2; ++j) {
            GLL16(gsrc[j] + ko,     Asp + b * TILE + ldso[j]);
            GLL16(gsrc[2 + j] + ko, Bsp + b * TILE + ldso[j]);
        }
    };

    f32x4 acc[MR][4] = {};
    ISSUE(0); ISSUE(1); ISSUE(2);

    for (int t = 0; t < NT; ++t) {
        if (t < NT - 2)       { asm volatile("s_waitcnt vmcnt(8)" ::: "memory"); }
        else if (t == NT - 2) { asm volatile("s_waitcnt vmcnt(4)" ::: "memory"); }
        else                  { asm volatile("s_waitcnt vmcnt(0)" ::: "memory"); }
        __builtin_amdgcn_sched_barrier(0);
        __builtin_amdgcn_s_barrier();
        __builtin_amdgcn_sched_barrier(0);

        const int b = t & 3;
        short8 af[MR], bf[4];
        #pragma unroll
        for (int m = 0; m < MR; ++m) af[m] = *(const short8*)(Asp + b * TILE + aoff[m]);
        #pragma unroll
        for (int n = 0; n < 4; ++n)  bf[n] = *(const short8*)(Bsp + b * TILE + boff[n]);
        if (t + 3 < NT) ISSUE(t + 3);
        __builtin_amdgcn_s_setprio(1);
        #pragma unroll
        for (int m = 0; m < MR; ++m)
            #pragma unroll
            for (int n = 0; n < 4; ++n)
                acc[m][n] = __builtin_amdgcn_mfma_f32_16x16x32_bf16(af[m], bf[n], acc[m][n], 0, 0, 0);
        __builtin_amdgcn_s_setprio(0);
    }

    if (EPI == 0 || EPI == 3) {
        __syncthreads();
        float* patch = (float*)((WAVES == 8 && (wv & 4)) ? (void*)Bsp : (void*)Asp)
                       + (wv & 3) * (16 * 68);
        const int cc0 = n0 + wc * 64;
        f32x4 bvv = {};
        if (EPI == 3) bvv = *(const f32x4*)(bias + cc0 + (lane & 15) * 4);
        float* C = (float*)Cout + (EPI == 0 ? (size_t)zidx * zstride : (size_t)0);
        #pragma unroll
        for (int m = 0; m < MR; ++m) {
            #pragma unroll
            for (int n = 0; n < 4; ++n)
                #pragma unroll
                for (int i = 0; i < 4; ++i)
                    patch[(ks * 4 + i) * 68 + n * 16 + lrow] = acc[m][n][i];
            #pragma unroll
            for (int i2 = 0; i2 < 4; ++i2) {
                const int prow = i2 * 4 + ks;
                f32x4 v = *(const f32x4*)(patch + prow * 68 + (lane & 15) * 4);
                if (EPI == 3) v += bvv;
                const int rr = m0 + wr * (BM / 2) + m * 16 + prow;
                *(f32x4*)(C + (size_t)rr * N + cc0 + (lane & 15) * 4) = v;
            }
        }
    } else {
        u16* C = (u16*)Cout;
        #pragma unroll
        for (int m = 0; m < MR; ++m) {
            const int rr = m0 + wr * (BM / 2) + m * 16 + ks * 4;
            #pragma unroll
            for (int n = 0; n < 4; ++n) {
                const int cc = n0 + wc * 64 + n * 16 + lrow;
                #pragma unroll
                for (int i = 0; i < 4; ++i) {
                    float vv = acc[m][n][i];
                    if (EPI == 2) vv = fmaxf(vv, 0.f);
                    C[(size_t)(rr + i) * N + cc] = f2b(vv);
                }
            }
        }
    }
}

template<int BM, int EPI>
__global__ __launch_bounds__(BM*2, 2) void gemm_pipe(
    const u16* __restrict__ A, const u16* __restrict__ Bt,
    void* __restrict__ Cout, const float* __restrict__ bias,
    int M, int N, int K, int lda, int ldb, size_t zstride)
{
    __shared__ __align__(16) u16 As[4][BM * 32];
    __shared__ __align__(16) u16 Bs[4][BM * 32];
    gemm_body<BM, EPI>(A, Bt, Cout, bias, M, N, K, lda, ldb, zstride,
                       blockIdx.x, gridDim.x, blockIdx.y, &As[0][0], &Bs[0][0]);
}

// Merged per-layer projection: blocks 0..255 = qk GEMM, 256..383 = vT GEMM
__global__ __launch_bounds__(256, 2) void gemm_qkv(
    const u16* __restrict__ xb, const u16* __restrict__ Wl,
    u16* __restrict__ qkbuf, u16* __restrict__ vTbuf)
{
    __shared__ __align__(16) u16 As[4][128 * 32];
    __shared__ __align__(16) u16 Bs[4][128 * 32];
    if (blockIdx.x < 256)
        gemm_body<128, 1>(xb, Wl, qkbuf, nullptr, MTOK, 2048, 1024, 1024, 1024, 0,
                          blockIdx.x, 256, 0, &As[0][0], &Bs[0][0]);
    else
        gemm_body<128, 1>(Wl + (size_t)2048 * 1024, xb, vTbuf, nullptr, 1024, MTOK, 1024,
                          1024, 1024, 0, blockIdx.x - 256, 128, 0, &As[0][0], &Bs[0][0]);
}

// ---------------------------------------------------------------------------
// Flash attention v5: un-paired grid (512 blocks, one q-tile each) with
// long/short co-scheduling: blocks 0-255 carry qt 15..8, 256-511 carry 0..7,
// so each CU hosts one long + one short block (8 waves resident).
__global__ __launch_bounds__(256, 2) void attn_flash5(
    const u16* __restrict__ qk, const u16* __restrict__ vT, float* __restrict__ delta)
{
    __shared__ __align__(16) u16 Qs[64 * 64];
    __shared__ __align__(16) u16 Kd[2][64 * 64];
    __shared__ __align__(16) u16 Vd[2][64 * 64];
    __shared__ __align__(16) u16 Ps[4][16 * 64];

    const int i = blockIdx.x;
    const int j = i & 255, rep = i >> 8;
    const int p8 = j >> 5, sub = j & 31;
    const int h = sub & 15, b = sub >> 4;
    const int qt = rep ? p8 : 15 - p8;

    const int tid = threadIdx.x, wv = tid >> 6, lane = tid & 63;
    const int lrow = lane & 15, ks4 = lane >> 4, li4 = ks4 * 4;
    const long baseQK = (long)b * NS * 2048;
    const u16* vbase = vT + (long)h * 64 * 2048 + b * NS;
    u16* ps = &Ps[wv][0];

    #pragma unroll
    for (int i2 = 0; i2 < 2; ++i2) {
        const int c = (wv * 2 + i2) * 64 + lane;
        const int row = c >> 3, u = (c & 7) ^ (row & 7);
        GLL16(qk + baseQK + (long)(qt * 64 + row) * 2048 + h * 64 + u * 8, Qs + c * 8);
        GLL16(qk + baseQK + (long)row * 2048 + 1024 + h * 64 + u * 8, Kd[0] + c * 8);
        GLL16(vbase + (long)row * 2048 + u * 8, Vd[0] + c * 8);
    }
    __syncthreads();

    short8 aq[2];
    {
        const int row = wv * 16 + lrow;
        aq[0] = *(const short8*)(Qs + row * 64 + ((ks4 ^ (row & 7)) * 8));
        aq[1] = *(const short8*)(Qs + row * 64 + (((4 + ks4) ^ (row & 7)) * 8));
    }

    f32x4 o[4] = {};
    float m_ = -__builtin_inff(), l_ = 0.f;

    for (int t = 0; t <= qt; ++t) {
        const int p = t & 1;
        if (t < qt) {
            #pragma unroll
            for (int i2 = 0; i2 < 2; ++i2) {
                const int c = (wv * 2 + i2) * 64 + lane;
                const int row = c >> 3, u = (c & 7) ^ (row & 7);
                GLL16(qk + baseQK + (long)((t + 1) * 64 + row) * 2048 + 1024 + h * 64 + u * 8, Kd[p ^ 1] + c * 8);
                GLL16(vbase + (long)row * 2048 + (t + 1) * 64 + u * 8, Vd[p ^ 1] + c * 8);
            }
        }
        f32x4 sa[4];
        #pragma unroll
        for (int nb = 0; nb < 4; ++nb) {
            f32x4 z = {};
            #pragma unroll
            for (int kd = 0; kd < 2; ++kd) {
                const int row = nb * 16 + lrow;
                short8 bk = *(const short8*)(Kd[p] + row * 64 + (((kd * 4 + ks4) ^ (row & 7)) * 8));
                z = __builtin_amdgcn_mfma_f32_16x16x32_bf16(bk, aq[kd], z, 0, 0, 0);
            }
            sa[nb] = z;
        }
        const int qg = qt * 64 + wv * 16 + lrow;
        #pragma unroll
        for (int nb = 0; nb < 4; ++nb)
            #pragma unroll
            for (int i3 = 0; i3 < 4; ++i3) {
                float sc = sa[nb][i3] * 0.125f;
                if (t == qt && (t * 64 + nb * 16 + li4 + i3) > qg) sc = -__builtin_inff();
                sa[nb][i3] = sc;
            }
        float mt = sa[0][0];
        #pragma unroll
        for (int nb = 0; nb < 4; ++nb)
            #pragma unroll
            for (int i3 = 0; i3 < 4; ++i3) mt = fmaxf(mt, sa[nb][i3]);
        mt = fmaxf(mt, __shfl_xor(mt, 16, 64));
        mt = fmaxf(mt, __shfl_xor(mt, 32, 64));
        const float mn = fmaxf(m_, mt);
        const float fac = expf(m_ - mn);
        m_ = mn;
        float rs = 0.f;
        #pragma unroll
        for (int nb = 0; nb < 4; ++nb)
            #pragma unroll
            for (int i3 = 0; i3 < 4; ++i3) {
                float pp = expf(sa[nb][i3] - mn);
                sa[nb][i3] = pp; rs += pp;
            }
        rs += __shfl_xor(rs, 16, 64);
        rs += __shfl_xor(rs, 32, 64);
        l_ = l_ * fac + rs;
        #pragma unroll
        for (int nd = 0; nd < 4; ++nd) o[nd] *= fac;

        #pragma unroll
        for (int nb = 0; nb < 4; ++nb) {
            u16 fourv[4];
            #pragma unroll
            for (int i3 = 0; i3 < 4; ++i3) fourv[i3] = f2b(sa[nb][i3]);
            const int kvb = nb * 16 + li4;
            const int addr = lrow * 64 + (((kvb >> 3) ^ (lrow & 7)) * 8) + (kvb & 7);
            *(short4_t*)(ps + addr) = *(const short4_t*)fourv;
        }
        short8 pa[2];
        pa[0] = *(const short8*)(ps + lrow * 64 + ((ks4 ^ (lrow & 7)) * 8));
        pa[1] = *(const short8*)(ps + lrow * 64 + (((4 + ks4) ^ (lrow & 7)) * 8));
        #pragma unroll
        for (int nd = 0; nd < 4; ++nd)
            #pragma unroll
            for (int kd = 0; kd < 2; ++kd) {
                const int row = nd * 16 + lrow;
                short8 vb = *(const short8*)(Vd[p] + row * 64 + (((kd * 4 + ks4) ^ (row & 7)) * 8));
                o[nd] = __builtin_amdgcn_mfma_f32_16x16x32_bf16(vb, pa[kd], o[nd], 0, 0, 0);
            }
        __syncthreads();
    }

    const float inv = 1.f / l_;
    const long tok = (long)b * NS + qt * 64 + wv * 16 + lrow;
    #pragma unroll
    for (int nd = 0; nd < 4; ++nd) {
        f32x4 v = o[nd] * inv;
        *(f32x4*)(delta + tok * DMODEL + h * 64 + nd * 16 + li4) = v;
    }
}

// ---------------------------------------------------------------------------
extern "C" void kernel_launch(void* const* d_in, const int* in_sizes, int n_in,
                              void* d_out, int out_size, void* d_ws, size_t ws_size,
                              hipStream_t stream) {
    const int*   toks  = (const int*)d_in[0];
    const float* emb   = (const float*)d_in[1];
    const float* Wq    = (const float*)d_in[2];
    const float* Wk    = (const float*)d_in[3];
    const float* Wv    = (const float*)d_in[4];
    const float* W1    = (const float*)d_in[5];
    const float* W2    = (const float*)d_in[6];
    const float* ln1g  = (const float*)d_in[7];
    const float* ln1b  = (const float*)d_in[8];
    const float* ln2g  = (const float*)d_in[9];
    const float* ln2b  = (const float*)d_in[10];
    const float* Wout  = (const float*)d_in[11];
    const float* bout  = (const float*)d_in[12];

    char* p = (char*)d_ws;
    auto alloc = [&](size_t bytes) { void* r = (void*)p; p += (bytes + 255) & ~(size_t)255; return r; };
    const size_t PSZ = (size_t)MTOK * 1024;
    u16*   Wqkv_t = (u16*)alloc((size_t)NLAYER * 3072 * 1024 * 2);
    u16*   W1t    = (u16*)alloc((size_t)NLAYER * 4096 * 1024 * 2);
    u16*   W2t    = (u16*)alloc((size_t)NLAYER * 1024 * 4096 * 2);
    u16*   Woutt  = (u16*)alloc((size_t)NVOCAB * 1024 * 2);
    float* x      = (float*)alloc((size_t)MTOK * 1024 * 4);
    u16*   xb     = (u16*)alloc((size_t)MTOK * 1024 * 2);
    u16*   qkbuf  = (u16*)alloc((size_t)MTOK * 2048 * 2);
    u16*   vTbuf  = (u16*)alloc((size_t)1024 * MTOK * 2);
    u16*   hbuf   = (u16*)alloc((size_t)MTOK * 4096 * 2);
    float* dbuf   = (float*)alloc(PSZ * 2 * 4);

    float* hbufF = (float*)hbuf;

    transpose_qkv<<<dim3(2, 32, 288), dim3(32, 8), 0, stream>>>(Wq, Wk, Wv, Wqkv_t);
    trans64<<<dim3(64, 16, 6), 256, 0, stream>>>(W1, W1t, 1024, 4096, 1024l * 4096, 4096l * 1024);
    trans64<<<dim3(16, 64, 6), 256, 0, stream>>>(W2, W2t, 4096, 1024, 4096l * 1024, 1024l * 4096);
    trans64<<<dim3(500, 16, 1), 256, 0, stream>>>(Wout, Woutt, 1024, NVOCAB, 0, 0);

    embed_pe<<<MTOK, 256, 0, stream>>>(toks, emb, x, xb);

    for (int l = 0; l < NLAYER; ++l) {
        const u16* Wl = Wqkv_t + (size_t)l * 3072 * 1024;
        gemm_qkv<<<dim3(384), 256, 0, stream>>>(xb, Wl, qkbuf, vTbuf);
        attn_flash5<<<dim3(512), 256, 0, stream>>>(qkbuf, vTbuf, hbufF);
        ln_residual<1><<<MTOK, 256, 0, stream>>>(x, hbufF, 0,
            ln1g + l * 1024, ln1b + l * 1024, x, xb);
        gemm_pipe<128, 2><<<dim3(16 * 32), 256, 0, stream>>>(
            xb, W1t + (size_t)l * 4096 * 1024, hbuf, nullptr, MTOK, 4096, 1024, 1024, 1024, 0);
        gemm_pipe<128, 0><<<dim3(16 * 8, 2), 256, 0, stream>>>(
            hbuf, W2t + (size_t)l * 1024 * 4096, dbuf, nullptr, MTOK, 1024, 2048, 4096, 4096, PSZ);
        ln_residual<2><<<MTOK, 256, 0, stream>>>(x, dbuf, PSZ,
            ln2g + l * 1024, ln2b + l * 1024, x, xb);
    }

    gemm_pipe<256, 3><<<dim3(8 * 125), 512, 0, stream>>>(
        xb, Woutt, (float*)d_out, bout, MTOK, NVOCAB, 1024, 1024, 1024, 0);
}

// Round 11
// 1107.945 us; speedup vs baseline: 1.0268x; 1.0268x over previous
//
#include <hip/hip_runtime.h>

typedef unsigned short u16;
typedef __attribute__((ext_vector_type(8))) short short8;
typedef __attribute__((ext_vector_type(4))) short short4_t;
typedef __attribute__((ext_vector_type(4))) float f32x4;

#define NLAYER 6
#define NH 16
#define DMODEL 1024
#define DHEAD 64
#define NVOCAB 32000
#define NB 2
#define NS 1024
#define NDFF 4096
#define MTOK (NB*NS)   // 2048

__device__ __forceinline__ u16 f2b(float f) {
    union { float f; unsigned u; } x; x.f = f;
    unsigned r = x.u + 0x7fffu + ((x.u >> 16) & 1u);
    return (u16)(r >> 16);
}

#define GLL16(gp, lp) __builtin_amdgcn_global_load_lds( \
    (const __attribute__((address_space(1))) void*)(gp), \
    (__attribute__((address_space(3))) void*)(lp), 16, 0, 0)

// ---------------------------------------------------------------------------
__global__ __launch_bounds__(256) void trans64(
    const float* __restrict__ src, u16* __restrict__ dst,
    int R, int C, long sStride, long dStride)
{
    __shared__ float sh[64][65];
    const int c0 = blockIdx.x * 64, r0 = blockIdx.y * 64;
    const float* s = src + (long)blockIdx.z * sStride;
    u16* d = dst + (long)blockIdx.z * dStride;
    const int tid = threadIdx.x;
    const int lr = tid >> 4, lc = (tid & 15) * 4;
    #pragma unroll
    for (int q = 0; q < 4; ++q) {
        const float4 v = *(const float4*)(s + (long)(r0 + q * 16 + lr) * C + c0 + lc);
        sh[q * 16 + lr][lc + 0] = v.x;
        sh[q * 16 + lr][lc + 1] = v.y;
        sh[q * 16 + lr][lc + 2] = v.z;
        sh[q * 16 + lr][lc + 3] = v.w;
    }
    __syncthreads();
    #pragma unroll
    for (int k = 0; k < 2; ++k) {
        const int t = tid + 256 * k;
        const int col = t >> 3, rch = (t & 7) * 8;
        u16 tmp[8];
        #pragma unroll
        for (int j = 0; j < 8; ++j) tmp[j] = f2b(sh[rch + j][col]);
        *(short8*)(d + (long)(c0 + col) * R + r0 + rch) = *(const short8*)tmp;
    }
}

// Wq/Wk/Wv merged: z = sel*96 + (l*16+h)
__global__ void transpose_qkv(const float* __restrict__ Wq, const float* __restrict__ Wk,
                              const float* __restrict__ Wv, u16* __restrict__ dst)
{
    __shared__ float t[32][33];
    const int sel = blockIdx.z / 96, bi = blockIdx.z % 96;
    const int l = bi >> 4, h = bi & 15;
    const float* srcs[3] = { Wq, Wk, Wv };
    const float* s = srcs[sel] + (long)bi * (DMODEL * DHEAD);
    u16* d = dst + (long)l * 3072 * DMODEL + (long)(sel * 1024 + h * 64) * DMODEL;
    const int c0 = blockIdx.x * 32, r0 = blockIdx.y * 32;
    const int tx = threadIdx.x, ty = threadIdx.y;
    #pragma unroll
    for (int j = 0; j < 32; j += 8)
        t[ty + j][tx] = s[(long)(r0 + ty + j) * DHEAD + c0 + tx];
    __syncthreads();
    #pragma unroll
    for (int j = 0; j < 32; j += 8)
        d[(long)(c0 + ty + j) * DMODEL + r0 + tx] = f2b(t[tx][ty + j]);
}

// ---------------------------------------------------------------------------
// Embedding + PE, f32x4 vectorized (thread handles 4 consecutive dims)
__global__ __launch_bounds__(256) void embed_pe(
    const int* __restrict__ toks, const float* __restrict__ emb,
    float* __restrict__ x, u16* __restrict__ xb)
{
    const int row = blockIdx.x;
    const int s = row & (NS - 1);
    const long erow = (long)toks[row] * DMODEL;
    const long base = (long)row * DMODEL;
    const int d = threadIdx.x * 4;
    f32x4 e = *(const f32x4*)(emb + erow + d);
    f32x4 v;
    #pragma unroll
    for (int j = 0; j < 4; ++j) {
        const int dd = d + j;
        float ang = (float)s * exp2f(-(float)dd * (9.965784284662087f / 1024.f));
        float pe = (dd & 1) ? cosf(ang) : sinf(ang);
        v[j] = e[j] + pe;
    }
    *(f32x4*)(x + base + d) = v;
    u16 fourv[4];
    #pragma unroll
    for (int j = 0; j < 4; ++j) fourv[j] = f2b(v[j]);
    *(short4_t*)(xb + base + d) = *(const short4_t*)fourv;
}

// ---------------------------------------------------------------------------
template<int ND>
__global__ __launch_bounds__(256) void ln_residual(
    const float* __restrict__ xin, const float* __restrict__ delta, size_t pstride,
    const float* __restrict__ g, const float* __restrict__ bb,
    float* __restrict__ xout, u16* __restrict__ xbout)
{
    __shared__ float red[8];
    const long base = (long)blockIdx.x * DMODEL;
    const int d = threadIdx.x * 4;
    f32x4 v = *(const f32x4*)(xin + base + d);
    #pragma unroll
    for (int y = 0; y < ND; ++y)
        v += *(const f32x4*)(delta + base + (size_t)y * pstride + d);
    float sum = v[0] + v[1] + v[2] + v[3];
    float sq  = v[0]*v[0] + v[1]*v[1] + v[2]*v[2] + v[3]*v[3];
    #pragma unroll
    for (int off = 1; off < 64; off <<= 1) {
        sum += __shfl_xor(sum, off, 64);
        sq  += __shfl_xor(sq,  off, 64);
    }
    const int wv = threadIdx.x >> 6, lane = threadIdx.x & 63;
    if (lane == 0) { red[wv] = sum; red[4 + wv] = sq; }
    __syncthreads();
    float ts = red[0] + red[1] + red[2] + red[3];
    float tq = red[4] + red[5] + red[6] + red[7];
    float mu = ts * (1.f / DMODEL);
    float var = tq * (1.f / DMODEL) - mu * mu;
    float rstd = rsqrtf(var + 1e-5f);
    const f32x4 gg = *(const f32x4*)(g + d);
    const f32x4 bv = *(const f32x4*)(bb + d);
    f32x4 yv = (v - mu) * rstd * gg + bv;
    *(f32x4*)(xout + base + d) = yv;
    u16 fourv[4];
    #pragma unroll
    for (int i = 0; i < 4; ++i) fourv[i] = f2b(yv[i]);
    *(short4_t*)(xbout + base + d) = *(const short4_t*)fourv;
}

// ---------------------------------------------------------------------------
// r5-proven pipelined GEMM body (16x16x32, BK=32, 4 LDS slots, vmcnt(8),
// XOR swizzle, XCD swizzle).
template<int BM, int EPI>
__device__ __forceinline__ void gemm_body(
    const u16* __restrict__ A, const u16* __restrict__ Bt,
    void* __restrict__ Cout, const float* __restrict__ bias,
    int M, int N, int K, int lda, int ldb, size_t zstride,
    int id, int nwg, int zidx, u16* Asp, u16* Bsp)
{
    constexpr int WAVES = BM / 32;
    constexpr int WC = WAVES / 2;
    constexpr int MR = BM / 32;
    constexpr int TILE = BM * 32;

    const int nmb = M / BM;
    const int q = nwg >> 3, r = nwg & 7, xcd = id & 7, loc = id >> 3;
    const int swz = (xcd < r ? xcd * (q + 1) : r * (q + 1) + (xcd - r) * q) + loc;
    const int m0 = (swz % nmb) * BM, n0 = (swz / nmb) * BM;
    const int koff = zidx * K;

    const int tid = threadIdx.x, wv = tid >> 6, lane = tid & 63;
    const int wr = wv / WC, wc = wv % WC;
    const int lrow = lane & 15, ks = lane >> 4;

    const u16* gsrc[4];
    int ldso[2];
    {
        const int l4 = lane >> 2, s = lane & 3;
        #pragma unroll
        for (int j = 0; j < 2; ++j) {
            const int row = j * (WAVES * 16) + wv * 16 + l4;
            const int x = (row >> 1) & 3;
            gsrc[j]     = A  + (size_t)(m0 + row) * lda + koff + (size_t)((s ^ x) * 8);
            gsrc[2 + j] = Bt + (size_t)(n0 + row) * ldb + koff + (size_t)((s ^ x) * 8);
            ldso[j] = (j * (WAVES * 16) + wv * 16) * 32;
        }
    }
    int aoff[MR], boff[4];
    #pragma unroll
    for (int m = 0; m < MR; ++m) {
        const int row = wr * (BM / 2) + m * 16 + lrow;
        aoff[m] = row * 32 + ((ks ^ ((row >> 1) & 3)) * 8);
    }
    #pragma unroll
    for (int n = 0; n < 4; ++n) {
        const int row = wc * 64 + n * 16 + lrow;
        boff[n] = row * 32 + ((ks ^ ((row >> 1) & 3)) * 8);
    }

    const int NT = K / 32;
    auto ISSUE = [&](int t) {
        const int b = t & 3;
        const size_t ko = (size_t)t * 32;
        #pragma unroll
        for (int j = 0; j < 2; ++j) {
            GLL16(gsrc[j] + ko,     Asp + b * TILE + ldso[j]);
            GLL16(gsrc[2 + j] + ko, Bsp + b * TILE + ldso[j]);
        }
    };

    f32x4 acc[MR][4] = {};
    ISSUE(0); ISSUE(1); ISSUE(2);

    for (int t = 0; t < NT; ++t) {
        if (t < NT - 2)       { asm volatile("s_waitcnt vmcnt(8)" ::: "memory"); }
        else if (t == NT - 2) { asm volatile("s_waitcnt vmcnt(4)" ::: "memory"); }
        else                  { asm volatile("s_waitcnt vmcnt(0)" ::: "memory"); }
        __builtin_amdgcn_sched_barrier(0);
        __builtin_amdgcn_s_barrier();
        __builtin_amdgcn_sched_barrier(0);

        const int b = t & 3;
        short8 af[MR], bf[4];
        #pragma unroll
        for (int m = 0; m < MR; ++m) af[m] = *(const short8*)(Asp + b * TILE + aoff[m]);
        #pragma unroll
        for (int n = 0; n < 4; ++n)  bf[n] = *(const short8*)(Bsp + b * TILE + boff[n]);
        if (t + 3 < NT) ISSUE(t + 3);
        __builtin_amdgcn_s_setprio(1);
        #pragma unroll
        for (int m = 0; m < MR; ++m)
            #pragma unroll
            for (int n = 0; n < 4; ++n)
                acc[m][n] = __builtin_amdgcn_mfma_f32_16x16x32_bf16(af[m], bf[n], acc[m][n], 0, 0, 0);
        __builtin_amdgcn_s_setprio(0);
    }

    if (EPI == 0 || EPI == 3) {
        __syncthreads();
        float* patch = (float*)((WAVES == 8 && (wv & 4)) ? (void*)Bsp : (void*)Asp)
                       + (wv & 3) * (16 * 68);
        const int cc0 = n0 + wc * 64;
        f32x4 bvv = {};
        if (EPI == 3) bvv = *(const f32x4*)(bias + cc0 + (lane & 15) * 4);
        float* C = (float*)Cout + (EPI == 0 ? (size_t)zidx * zstride : (size_t)0);
        #pragma unroll
        for (int m = 0; m < MR; ++m) {
            #pragma unroll
            for (int n = 0; n < 4; ++n)
                #pragma unroll
                for (int i = 0; i < 4; ++i)
                    patch[(ks * 4 + i) * 68 + n * 16 + lrow] = acc[m][n][i];
            #pragma unroll
            for (int i2 = 0; i2 < 4; ++i2) {
                const int prow = i2 * 4 + ks;
                f32x4 v = *(const f32x4*)(patch + prow * 68 + (lane & 15) * 4);
                if (EPI == 3) v += bvv;
                const int rr = m0 + wr * (BM / 2) + m * 16 + prow;
                *(f32x4*)(C + (size_t)rr * N + cc0 + (lane & 15) * 4) = v;
            }
        }
    } else {
        u16* C = (u16*)Cout;
        #pragma unroll
        for (int m = 0; m < MR; ++m) {
            const int rr = m0 + wr * (BM / 2) + m * 16 + ks * 4;
            #pragma unroll
            for (int n = 0; n < 4; ++n) {
                const int cc = n0 + wc * 64 + n * 16 + lrow;
                #pragma unroll
                for (int i = 0; i < 4; ++i) {
                    float vv = acc[m][n][i];
                    if (EPI == 2) vv = fmaxf(vv, 0.f);
                    C[(size_t)(rr + i) * N + cc] = f2b(vv);
                }
            }
        }
    }
}

template<int BM, int EPI>
__global__ __launch_bounds__(BM*2, 2) void gemm_pipe(
    const u16* __restrict__ A, const u16* __restrict__ Bt,
    void* __restrict__ Cout, const float* __restrict__ bias,
    int M, int N, int K, int lda, int ldb, size_t zstride)
{
    __shared__ __align__(16) u16 As[4][BM * 32];
    __shared__ __align__(16) u16 Bs[4][BM * 32];
    gemm_body<BM, EPI>(A, Bt, Cout, bias, M, N, K, lda, ldb, zstride,
                       blockIdx.x, gridDim.x, blockIdx.y, &As[0][0], &Bs[0][0]);
}

// Merged per-layer projection: blocks 0..255 = qk GEMM, 256..383 = vT GEMM
__global__ __launch_bounds__(256, 2) void gemm_qkv(
    const u16* __restrict__ xb, const u16* __restrict__ Wl,
    u16* __restrict__ qkbuf, u16* __restrict__ vTbuf)
{
    __shared__ __align__(16) u16 As[4][128 * 32];
    __shared__ __align__(16) u16 Bs[4][128 * 32];
    if (blockIdx.x < 256)
        gemm_body<128, 1>(xb, Wl, qkbuf, nullptr, MTOK, 2048, 1024, 1024, 1024, 0,
                          blockIdx.x, 256, 0, &As[0][0], &Bs[0][0]);
    else
        gemm_body<128, 1>(Wl + (size_t)2048 * 1024, xb, vTbuf, nullptr, 1024, MTOK, 1024,
                          1024, 1024, 0, blockIdx.x - 256, 128, 0, &As[0][0], &Bs[0][0]);
}

// ---------------------------------------------------------------------------
// Flash attention v4 (r9-exact, paired): swapped-operand S^T = mfma(K,Q),
// scalar m/l, b64 P-stores, V^T staged via global_load_lds, dbuf K/V.
__global__ __launch_bounds__(256, 2) void attn_flash4(
    const u16* __restrict__ qk, const u16* __restrict__ vT, float* __restrict__ delta)
{
    __shared__ __align__(16) u16 Qs[64 * 64];
    __shared__ __align__(16) u16 Kd[2][64 * 64];
    __shared__ __align__(16) u16 Vd[2][64 * 64];
    __shared__ __align__(16) u16 Ps[4][16 * 64];

    const int pair = blockIdx.x, h = blockIdx.y, b = blockIdx.z;
    const int tid = threadIdx.x, wv = tid >> 6, lane = tid & 63;
    const int lrow = lane & 15, ks4 = lane >> 4, li4 = ks4 * 4;
    const long baseQK = (long)b * NS * 2048;
    const u16* vbase = vT + (long)h * 64 * 2048 + b * NS;
    u16* ps = &Ps[wv][0];

    for (int rep = 0; rep < 2; ++rep) {
        const int qt = rep ? 15 - pair : pair;
        __syncthreads();

        #pragma unroll
        for (int i = 0; i < 2; ++i) {
            const int c = (wv * 2 + i) * 64 + lane;
            const int row = c >> 3, u = (c & 7) ^ (row & 7);
            GLL16(qk + baseQK + (long)(qt * 64 + row) * 2048 + h * 64 + u * 8, Qs + c * 8);
            GLL16(qk + baseQK + (long)row * 2048 + 1024 + h * 64 + u * 8, Kd[0] + c * 8);
            GLL16(vbase + (long)row * 2048 + u * 8, Vd[0] + c * 8);
        }
        __syncthreads();

        short8 aq[2];
        {
            const int row = wv * 16 + lrow;
            aq[0] = *(const short8*)(Qs + row * 64 + ((ks4 ^ (row & 7)) * 8));
            aq[1] = *(const short8*)(Qs + row * 64 + (((4 + ks4) ^ (row & 7)) * 8));
        }

        f32x4 o[4] = {};
        float m_ = -__builtin_inff(), l_ = 0.f;

        for (int t = 0; t <= qt; ++t) {
            const int p = t & 1;
            if (t < qt) {
                #pragma unroll
                for (int i = 0; i < 2; ++i) {
                    const int c = (wv * 2 + i) * 64 + lane;
                    const int row = c >> 3, u = (c & 7) ^ (row & 7);
                    GLL16(qk + baseQK + (long)((t + 1) * 64 + row) * 2048 + 1024 + h * 64 + u * 8, Kd[p ^ 1] + c * 8);
                    GLL16(vbase + (long)row * 2048 + (t + 1) * 64 + u * 8, Vd[p ^ 1] + c * 8);
                }
            }
            f32x4 sa[4];
            #pragma unroll
            for (int nb = 0; nb < 4; ++nb) {
                f32x4 z = {};
                #pragma unroll
                for (int kd = 0; kd < 2; ++kd) {
                    const int row = nb * 16 + lrow;
                    short8 bk = *(const short8*)(Kd[p] + row * 64 + (((kd * 4 + ks4) ^ (row & 7)) * 8));
                    z = __builtin_amdgcn_mfma_f32_16x16x32_bf16(bk, aq[kd], z, 0, 0, 0);
                }
                sa[nb] = z;
            }
            const int qg = qt * 64 + wv * 16 + lrow;
            #pragma unroll
            for (int nb = 0; nb < 4; ++nb)
                #pragma unroll
                for (int i = 0; i < 4; ++i) {
                    float sc = sa[nb][i] * 0.125f;
                    if (t == qt && (t * 64 + nb * 16 + li4 + i) > qg) sc = -__builtin_inff();
                    sa[nb][i] = sc;
                }
            float mt = sa[0][0];
            #pragma unroll
            for (int nb = 0; nb < 4; ++nb)
                #pragma unroll
                for (int i = 0; i < 4; ++i) mt = fmaxf(mt, sa[nb][i]);
            mt = fmaxf(mt, __shfl_xor(mt, 16, 64));
            mt = fmaxf(mt, __shfl_xor(mt, 32, 64));
            const float mn = fmaxf(m_, mt);
            const float fac = expf(m_ - mn);
            m_ = mn;
            float rs = 0.f;
            #pragma unroll
            for (int nb = 0; nb < 4; ++nb)
                #pragma unroll
                for (int i = 0; i < 4; ++i) {
                    float pp = expf(sa[nb][i] - mn);
                    sa[nb][i] = pp; rs += pp;
                }
            rs += __shfl_xor(rs, 16, 64);
            rs += __shfl_xor(rs, 32, 64);
            l_ = l_ * fac + rs;
            #pragma unroll
            for (int nd = 0; nd < 4; ++nd) o[nd] *= fac;

            #pragma unroll
            for (int nb = 0; nb < 4; ++nb) {
                u16 fourv[4];
                #pragma unroll
                for (int i = 0; i < 4; ++i) fourv[i] = f2b(sa[nb][i]);
                const int kvb = nb * 16 + li4;
                const int addr = lrow * 64 + (((kvb >> 3) ^ (lrow & 7)) * 8) + (kvb & 7);
                *(short4_t*)(ps + addr) = *(const short4_t*)fourv;
            }
            short8 pa[2];
            pa[0] = *(const short8*)(ps + lrow * 64 + ((ks4 ^ (lrow & 7)) * 8));
            pa[1] = *(const short8*)(ps + lrow * 64 + (((4 + ks4) ^ (lrow & 7)) * 8));
            #pragma unroll
            for (int nd = 0; nd < 4; ++nd)
                #pragma unroll
                for (int kd = 0; kd < 2; ++kd) {
                    const int row = nd * 16 + lrow;
                    short8 vb = *(const short8*)(Vd[p] + row * 64 + (((kd * 4 + ks4) ^ (row & 7)) * 8));
                    o[nd] = __builtin_amdgcn_mfma_f32_16x16x32_bf16(vb, pa[kd], o[nd], 0, 0, 0);
                }
            __syncthreads();
        }

        const float inv = 1.f / l_;
        const long tok = (long)b * NS + qt * 64 + wv * 16 + lrow;
        #pragma unroll
        for (int nd = 0; nd < 4; ++nd) {
            f32x4 v = o[nd] * inv;
            *(f32x4*)(delta + tok * DMODEL + h * 64 + nd * 16 + li4) = v;
        }
    }
}

// ---------------------------------------------------------------------------
extern "C" void kernel_launch(void* const* d_in, const int* in_sizes, int n_in,
                              void* d_out, int out_size, void* d_ws, size_t ws_size,
                              hipStream_t stream) {
    const int*   toks  = (const int*)d_in[0];
    const float* emb   = (const float*)d_in[1];
    const float* Wq    = (const float*)d_in[2];
    const float* Wk    = (const float*)d_in[3];
    const float* Wv    = (const float*)d_in[4];
    const float* W1    = (const float*)d_in[5];
    const float* W2    = (const float*)d_in[6];
    const float* ln1g  = (const float*)d_in[7];
    const float* ln1b  = (const float*)d_in[8];
    const float* ln2g  = (const float*)d_in[9];
    const float* ln2b  = (const float*)d_in[10];
    const float* Wout  = (const float*)d_in[11];
    const float* bout  = (const float*)d_in[12];

    char* p = (char*)d_ws;
    auto alloc = [&](size_t bytes) { void* r = (void*)p; p += (bytes + 255) & ~(size_t)255; return r; };
    const size_t PSZ = (size_t)MTOK * 1024;
    u16*   Wqkv_t = (u16*)alloc((size_t)NLAYER * 3072 * 1024 * 2);
    u16*   W1t    = (u16*)alloc((size_t)NLAYER * 4096 * 1024 * 2);
    u16*   W2t    = (u16*)alloc((size_t)NLAYER * 1024 * 4096 * 2);
    u16*   Woutt  = (u16*)alloc((size_t)NVOCAB * 1024 * 2);
    float* x      = (float*)alloc((size_t)MTOK * 1024 * 4);
    u16*   xb     = (u16*)alloc((size_t)MTOK * 1024 * 2);
    u16*   qkbuf  = (u16*)alloc((size_t)MTOK * 2048 * 2);
    u16*   vTbuf  = (u16*)alloc((size_t)1024 * MTOK * 2);
    u16*   hbuf   = (u16*)alloc((size_t)MTOK * 4096 * 2);
    float* dbuf   = (float*)alloc(PSZ * 2 * 4);

    float* hbufF = (float*)hbuf;

    transpose_qkv<<<dim3(2, 32, 288), dim3(32, 8), 0, stream>>>(Wq, Wk, Wv, Wqkv_t);
    trans64<<<dim3(64, 16, 6), 256, 0, stream>>>(W1, W1t, 1024, 4096, 1024l * 4096, 4096l * 1024);
    trans64<<<dim3(16, 64, 6), 256, 0, stream>>>(W2, W2t, 4096, 1024, 4096l * 1024, 1024l * 4096);
    trans64<<<dim3(500, 16, 1), 256, 0, stream>>>(Wout, Woutt, 1024, NVOCAB, 0, 0);

    embed_pe<<<MTOK, 256, 0, stream>>>(toks, emb, x, xb);

    for (int l = 0; l < NLAYER; ++l) {
        const u16* Wl = Wqkv_t + (size_t)l * 3072 * 1024;
        gemm_qkv<<<dim3(384), 256, 0, stream>>>(xb, Wl, qkbuf, vTbuf);
        attn_flash4<<<dim3(8, NH, NB), 256, 0, stream>>>(qkbuf, vTbuf, hbufF);
        ln_residual<1><<<MTOK, 256, 0, stream>>>(x, hbufF, 0,
            ln1g + l * 1024, ln1b + l * 1024, x, xb);
        gemm_pipe<128, 2><<<dim3(16 * 32), 256, 0, stream>>>(
            xb, W1t + (size_t)l * 4096 * 1024, hbuf, nullptr, MTOK, 4096, 1024, 1024, 1024, 0);
        gemm_pipe<128, 0><<<dim3(16 * 8, 2), 256, 0, stream>>>(
            hbuf, W2t + (size_t)l * 1024 * 4096, dbuf, nullptr, MTOK, 1024, 2048, 4096, 4096, PSZ);
        ln_residual<2><<<MTOK, 256, 0, stream>>>(x, dbuf, PSZ,
            ln2g + l * 1024, ln2b + l * 1024, x, xb);
    }

    gemm_pipe<256, 3><<<dim3(8 * 125), 512, 0, stream>>>(
        xb, Woutt, (float*)d_out, bout, MTOK, NVOCAB, 1024, 1024, 1024, 0);
}